// Round 1
// baseline (445.191 us; speedup 1.0000x reference)
//
#include <hip/hip_runtime.h>

// SpatialMemoryGrid update, wave-per-cell-pair streaming kernel.
//
// Geometry (fixed by the reference):
//   B=4, GH=64, GW=64, N=16, F=256, DECAY=0.95
//   cells = B*GH*GW*N = 262144; out row = 258 floats (1032 B).
//
// Key trick: a PAIR of consecutive cells is 2*258 = 516 floats = 2064 B
// = exactly 129 float4s, and pair base (p*2064) is 16B-aligned, while a
// single odd cell is only 8B-aligned. One 64-lane wave owns one pair:
//   - loads state rows A,B as aligned dwordx4 (input stride 1024 B),
//   - stores op[lane]        = A'[4l..4l+3]                    (j=0..63)
//   - stores op[64+lane]     = {prevB'.z, prevB'.w, B'.x, B'.y} (j=64..127)
//       where prev = __shfl_up(B',1); lane 0 splices {confA', tempA'}
//   - lane 63 stores op[128] = {B'.z, B'.w, confB', tempB'}
// The update (blend) predicate depends only on the cell -> wave-uniform
// branch, costs ~nothing for the 262080/262144 non-updated cells.

#define GH 64
#define GW 64
#define NOBJ 16
#define FEAT 256
#define DECAYF 0.95f

__global__ __launch_bounds__(256) void smg_kernel(
    const float* __restrict__ grid_state,      // [B,GH,GW,N,F]
    const float* __restrict__ grid_conf,       // [B,GH,GW,N]
    const float* __restrict__ grid_temp,       // [B,GH,GW,N]
    const float* __restrict__ obj_feat,        // [B,N,F]
    const float* __restrict__ positions,       // [B,N,2]
    const float* __restrict__ occl,            // [B,N]
    float* __restrict__ out,                   // [B,GH,GW,N,258]
    int npairs, int nwaves)
{
    const int wave = (blockIdx.x * blockDim.x + threadIdx.x) >> 6;
    const int lane = threadIdx.x & 63;

    for (int p = wave; p < npairs; p += nwaves) {
        const int cellA = p << 1;              // even cell
        const int oA = cellA & (NOBJ - 1);     // even object index
        const int gw = (cellA >> 4)  & (GW - 1);
        const int gh = (cellA >> 10) & (GH - 1);
        const int b  = cellA >> 16;
        const int boA = b * NOBJ + oA;         // even -> 16B-aligned pos quad

        // ---- loads --------------------------------------------------
        const float4* sA = (const float4*)grid_state + (size_t)cellA * (FEAT / 4);
        float4 qA = sA[lane];                  // A state quad (aligned)
        float4 qB = sA[(FEAT / 4) + lane];     // B state quad (aligned)

        float2 cf = *(const float2*)(grid_conf + cellA);   // {confA, confB}
        float2 tp = *(const float2*)(grid_temp + cellA);   // {tempA, tempB}

        // positions for both objects of the pair: {pxA,pyA,pxB,pyB}
        float4 pos = *(const float4*)(positions + (size_t)boA * 2);
        float2 oc  = *(const float2*)(occl + boA);         // {occA, occB}

        // ---- update predicates (wave-uniform) -----------------------
        const int gwtA = (int)fminf(fmaxf(pos.x * (float)(GW - 1), 0.0f), 63.0f);
        const int ghtA = (int)fminf(fmaxf(pos.y * (float)(GH - 1), 0.0f), 63.0f);
        const int gwtB = (int)fminf(fmaxf(pos.z * (float)(GW - 1), 0.0f), 63.0f);
        const int ghtB = (int)fminf(fmaxf(pos.w * (float)(GH - 1), 0.0f), 63.0f);
        const bool updA = (gw == gwtA) && (gh == ghtA);
        const bool updB = (gw == gwtB) && (gh == ghtB);

        if (updA) {
            const bool  vis = oc.x < 0.5f;
            const float al  = vis ? 0.8f : 0.3f;
            const float be  = 1.0f - al;
            float4 w = ((const float4*)obj_feat)[(size_t)boA * (FEAT / 4) + lane];
            qA.x = al * w.x + be * qA.x;
            qA.y = al * w.y + be * qA.y;
            qA.z = al * w.z + be * qA.z;
            qA.w = al * w.w + be * qA.w;
            cf.x = vis ? fminf(1.0f, cf.x * 0.9f + 0.5f) : cf.x * DECAYF;
            tp.x += vis ? 1.0f : 0.5f;
        }
        if (updB) {
            const bool  vis = oc.y < 0.5f;
            const float al  = vis ? 0.8f : 0.3f;
            const float be  = 1.0f - al;
            float4 w = ((const float4*)obj_feat)[((size_t)boA + 1) * (FEAT / 4) + lane];
            qB.x = al * w.x + be * qB.x;
            qB.y = al * w.y + be * qB.y;
            qB.z = al * w.z + be * qB.z;
            qB.w = al * w.w + be * qB.w;
            cf.y = vis ? fminf(1.0f, cf.y * 0.9f + 0.5f) : cf.y * DECAYF;
            tp.y += vis ? 1.0f : 0.5f;
        }
        cf.x *= DECAYF;                        // global decay, all cells
        cf.y *= DECAYF;

        // ---- stores: 129 aligned float4s per pair -------------------
        float4* op = (float4*)(out + (size_t)p * 516);

        op[lane] = qA;                         // j = 0..63 : A state

        // j = 64+lane : {B'[4l-2], B'[4l-1], B'[4l], B'[4l+1]}
        float pz = __shfl_up(qB.z, 1, 64);
        float pw = __shfl_up(qB.w, 1, 64);
        if (lane == 0) { pz = cf.x; pw = tp.x; }   // splice confA', tempA'
        op[64 + lane] = make_float4(pz, pw, qB.x, qB.y);

        if (lane == 63) {                      // j = 128 : tail of B + confB'/tempB'
            op[128] = make_float4(qB.z, qB.w, cf.y, tp.y);
        }
    }
}

extern "C" void kernel_launch(void* const* d_in, const int* in_sizes, int n_in,
                              void* d_out, int out_size, void* d_ws, size_t ws_size,
                              hipStream_t stream) {
    const float* grid_state = (const float*)d_in[0];
    const float* grid_conf  = (const float*)d_in[1];
    const float* grid_temp  = (const float*)d_in[2];
    const float* obj_feat   = (const float*)d_in[3];
    const float* positions  = (const float*)d_in[4];
    const float* occl       = (const float*)d_in[5];
    float* out = (float*)d_out;

    const int B = in_sizes[5] / NOBJ;                 // 4
    const int cells  = B * GH * GW * NOBJ;            // 262144
    const int npairs = cells / 2;                     // 131072

    const int blocks = 2048;                          // grid-stride (G11)
    const int nwaves = blocks * (256 / 64);           // 8192 -> 16 pairs/wave

    smg_kernel<<<blocks, 256, 0, stream>>>(grid_state, grid_conf, grid_temp,
                                           obj_feat, positions, occl, out,
                                           npairs, nwaves);
}

// Round 2
// 443.581 us; speedup vs baseline: 1.0036x; 1.0036x over previous
//
#include <hip/hip_runtime.h>

// SpatialMemoryGrid update, wave-per-cell-pair streaming kernel (v2: nontemporal).
//
// Geometry (fixed by the reference):
//   B=4, GH=64, GW=64, N=16, F=256, DECAY=0.95
//   cells = B*GH*GW*N = 262144; out row = 258 floats (1032 B).
//
// A PAIR of consecutive cells is 2*258 = 516 floats = 2064 B = exactly 129
// float4s, and the pair base (p*2064) is 16B-aligned. One 64-lane wave owns
// one pair:
//   - loads state rows A,B as aligned dwordx4 (input stride 1024 B),
//   - stores op[lane]      = A'[4l..4l+3]                     (j=0..63)
//   - stores op[64+lane]   = {prevB'.z, prevB'.w, B'.x, B'.y} (j=64..127)
//       where prev = __shfl_up(B',1); lane 0 splices {confA', tempA'}
//   - lane 63 stores op[128] = {B'.z, B'.w, confB', tempB'}
// Update predicate is wave-uniform -> s_cbranch_execz skip for the
// 262080/262144 non-updated cells.
//
// v2: all bulk state loads/stores are nontemporal (streaming data, zero
// reuse — keep it out of L2/LLC; the harness fills sustain 6.55 TB/s on
// pure-write streams, we want the same treatment). Pair loop unrolled x2.

#define GH 64
#define GW 64
#define NOBJ 16
#define FEAT 256
#define DECAYF 0.95f

typedef float f4 __attribute__((ext_vector_type(4)));
typedef float f2 __attribute__((ext_vector_type(2)));

__global__ __launch_bounds__(256) void smg_kernel(
    const float* __restrict__ grid_state,      // [B,GH,GW,N,F]
    const float* __restrict__ grid_conf,       // [B,GH,GW,N]
    const float* __restrict__ grid_temp,       // [B,GH,GW,N]
    const float* __restrict__ obj_feat,        // [B,N,F]
    const float* __restrict__ positions,       // [B,N,2]
    const float* __restrict__ occl,            // [B,N]
    float* __restrict__ out,                   // [B,GH,GW,N,258]
    int npairs, int nwaves)
{
    const int wave = (blockIdx.x * blockDim.x + threadIdx.x) >> 6;
    const int lane = threadIdx.x & 63;

    #pragma unroll 2
    for (int p = wave; p < npairs; p += nwaves) {
        const int cellA = p << 1;              // even cell
        const int oA = cellA & (NOBJ - 1);     // even object index
        const int gw = (cellA >> 4)  & (GW - 1);
        const int gh = (cellA >> 10) & (GH - 1);
        const int b  = cellA >> 16;
        const int boA = b * NOBJ + oA;         // even -> 16B-aligned pos quad

        // ---- loads (nontemporal: zero reuse) ------------------------
        const f4* sA = (const f4*)grid_state + (size_t)cellA * (FEAT / 4);
        f4 qA = __builtin_nontemporal_load(sA + lane);            // A state quad
        f4 qB = __builtin_nontemporal_load(sA + (FEAT / 4) + lane); // B state quad

        f2 cf = *(const f2*)(grid_conf + cellA);   // {confA, confB}
        f2 tp = *(const f2*)(grid_temp + cellA);   // {tempA, tempB}

        // positions for both objects of the pair: {pxA,pyA,pxB,pyB}
        f4 pos = *(const f4*)(positions + (size_t)boA * 2);
        f2 oc  = *(const f2*)(occl + boA);         // {occA, occB}

        // ---- update predicates (wave-uniform) -----------------------
        const int gwtA = (int)fminf(fmaxf(pos.x * (float)(GW - 1), 0.0f), 63.0f);
        const int ghtA = (int)fminf(fmaxf(pos.y * (float)(GH - 1), 0.0f), 63.0f);
        const int gwtB = (int)fminf(fmaxf(pos.z * (float)(GW - 1), 0.0f), 63.0f);
        const int ghtB = (int)fminf(fmaxf(pos.w * (float)(GH - 1), 0.0f), 63.0f);
        const bool updA = (gw == gwtA) && (gh == ghtA);
        const bool updB = (gw == gwtB) && (gh == ghtB);

        if (updA) {
            const bool  vis = oc.x < 0.5f;
            const float al  = vis ? 0.8f : 0.3f;
            const float be  = 1.0f - al;
            f4 w = ((const f4*)obj_feat)[(size_t)boA * (FEAT / 4) + lane];
            qA.x = al * w.x + be * qA.x;
            qA.y = al * w.y + be * qA.y;
            qA.z = al * w.z + be * qA.z;
            qA.w = al * w.w + be * qA.w;
            cf.x = vis ? fminf(1.0f, cf.x * 0.9f + 0.5f) : cf.x * DECAYF;
            tp.x += vis ? 1.0f : 0.5f;
        }
        if (updB) {
            const bool  vis = oc.y < 0.5f;
            const float al  = vis ? 0.8f : 0.3f;
            const float be  = 1.0f - al;
            f4 w = ((const f4*)obj_feat)[((size_t)boA + 1) * (FEAT / 4) + lane];
            qB.x = al * w.x + be * qB.x;
            qB.y = al * w.y + be * qB.y;
            qB.z = al * w.z + be * qB.z;
            qB.w = al * w.w + be * qB.w;
            cf.y = vis ? fminf(1.0f, cf.y * 0.9f + 0.5f) : cf.y * DECAYF;
            tp.y += vis ? 1.0f : 0.5f;
        }
        cf.x *= DECAYF;                        // global decay, all cells
        cf.y *= DECAYF;

        // ---- stores: 129 aligned float4s per pair (nontemporal) -----
        f4* op = (f4*)(out + (size_t)p * 516);

        __builtin_nontemporal_store(qA, op + lane);    // j = 0..63 : A state

        // j = 64+lane : {B'[4l-2], B'[4l-1], B'[4l], B'[4l+1]}
        float pz = __shfl_up(qB.z, 1, 64);
        float pw = __shfl_up(qB.w, 1, 64);
        if (lane == 0) { pz = cf.x; pw = tp.x; }       // splice confA', tempA'
        f4 mid = {pz, pw, qB.x, qB.y};
        __builtin_nontemporal_store(mid, op + 64 + lane);

        if (lane == 63) {                      // j = 128 : tail of B + confB'/tempB'
            f4 tail = {qB.z, qB.w, cf.y, tp.y};
            __builtin_nontemporal_store(tail, op + 128);
        }
    }
}

extern "C" void kernel_launch(void* const* d_in, const int* in_sizes, int n_in,
                              void* d_out, int out_size, void* d_ws, size_t ws_size,
                              hipStream_t stream) {
    const float* grid_state = (const float*)d_in[0];
    const float* grid_conf  = (const float*)d_in[1];
    const float* grid_temp  = (const float*)d_in[2];
    const float* obj_feat   = (const float*)d_in[3];
    const float* positions  = (const float*)d_in[4];
    const float* occl       = (const float*)d_in[5];
    float* out = (float*)d_out;

    const int B = in_sizes[5] / NOBJ;                 // 4
    const int cells  = B * GH * GW * NOBJ;            // 262144
    const int npairs = cells / 2;                     // 131072

    const int blocks = 2048;                          // grid-stride (G11)
    const int nwaves = blocks * (256 / 64);           // 8192 -> 16 pairs/wave

    smg_kernel<<<blocks, 256, 0, stream>>>(grid_state, grid_conf, grid_temp,
                                           obj_feat, positions, occl, out,
                                           npairs, nwaves);
}